// Round 8
// baseline (4309.879 us; speedup 1.0000x reference)
//
#include <hip/hip_runtime.h>
#include <hip/hip_bf16.h>
#include <hip/hip_fp16.h>

#define SEQ   320
#define GATES 1600
#define NCOL  3200
#define GDW   16    // workgroups per direction in the recurrent kernel
#define RPW   25    // h-rows owned per workgroup (400/16)
#define EXL   (GDW * 2 * 322 * 16)   // dwords per layer exchange (322 slots: +2 boundary)

typedef _Float16 half2v __attribute__((ext_vector_type(2)));
typedef _Float16 f16x8  __attribute__((ext_vector_type(8)));
typedef float    f32x4  __attribute__((ext_vector_type(4)));
union H2U { unsigned u; half2v h; __half2 hh; };

// ---------------------------------------------------------------- prep: embed->f16, bias, cvt W_ih_l0/l1, ex boundary fill
__global__ __launch_bounds__(256) void prep_kernel(
    const int* __restrict__ words, const int* __restrict__ tags,
    const float* __restrict__ wemb, const float* __restrict__ temb,
    _Float16* __restrict__ Ah0,
    const float* __restrict__ bihl0,  const float* __restrict__ bhhl0,
    const float* __restrict__ bihl0r, const float* __restrict__ bhhl0r,
    const float* __restrict__ bihl1,  const float* __restrict__ bhhl1,
    const float* __restrict__ bihl1r, const float* __restrict__ bhhl1r,
    const float* __restrict__ mlpb1,
    float* __restrict__ bL0, float* __restrict__ bL1, float* __restrict__ bAB,
    const float* __restrict__ wih0, const float* __restrict__ wih0r,
    _Float16* __restrict__ BhA,
    const float* __restrict__ wih1, const float* __restrict__ wih1r,
    _Float16* __restrict__ BhB,
    const float* __restrict__ h0, unsigned* __restrict__ ex)
{
    const int b = blockIdx.x, t = threadIdx.x;
    if (b < 520) {                       // embeddings -> Ah0 (320 x 416, zero-pad)
        int i = b * 256 + t;
        if (i >= SEQ * 416) return;
        int tt = i / 416, c = i % 416;
        float v = 0.f;
        if (c < 300)      v = wemb[(size_t)words[tt] * 300 + c];
        else if (c < 400) v = temb[(size_t)tags[tt] * 100 + (c - 300)];
        Ah0[i] = (_Float16)v;
    } else if (b < 533) {                // bias sums
        int g = (b - 520) * 256 + t;
        if (g >= NCOL) return;
        if (g < GATES) {
            bL0[g] = bihl0[g] + bhhl0[g];
            bL1[g] = bihl1[g] + bhhl1[g];
            bAB[g] = mlpb1[g];
        } else {
            int q = g - GATES;
            bL0[g] = bihl0r[q] + bhhl0r[q];
            bL1[g] = bihl1r[q] + bhhl1r[q];
            bAB[g] = 0.f;
        }
    } else if (b < 5733) {               // W_ih_l0 -> fp16 (3200 x 416)
        int i = (b - 533) * 256 + t;
        if (i >= NCOL * 416) return;
        int n = i / 416, k = i % 416;
        float v = 0.f;
        if (k < 400)
            v = (n < GATES) ? wih0[(size_t)n * 400 + k]
                            : wih0r[(size_t)(n - GATES) * 400 + k];
        BhA[i] = (_Float16)v;
    } else if (b < 15733) {              // W_ih_l1 -> fp16 (3200 x 800)
        int i = (b - 5733) * 256 + t;
        if (i >= NCOL * 800) return;
        int n = i / 800, k = i % 800;
        BhB[i] = (_Float16)((n < GATES) ? wih1[(size_t)n * 800 + k]
                                        : wih1r[(size_t)(n - GATES) * 800 + k]);
    } else {                             // h0 -> exchange boundary lines (64 lines)
        if (t >= 64) return;
        int layer = t >> 5, dir = (t >> 4) & 1, p = t & 15;
        const float* hsrc = h0 + (size_t)(layer * 2 + dir) * 400 + p * 25;
        unsigned slot = dir ? 321u : 0u;
        unsigned* line = ex + (size_t)layer * EXL +
                         (((unsigned)dir * GDW + p) * 322 + slot) * 16;
        for (int d = 0; d < 13; ++d) {
            float lo = hsrc[2 * d];
            float hi = (2 * d + 1 < RPW) ? hsrc[2 * d + 1] : 0.f;
            H2U pk; pk.hh = __floats2half2_rn(lo, hi);
            line[d] = pk.u;
        }
    }
}

// ---------------------------------------------------------------- cvt mlp_w1 -> BhA (after gemm0 frees it)
__global__ __launch_bounds__(256) void cvtMLP_kernel(
    const float* __restrict__ mlpw1, _Float16* __restrict__ BhA)
{
    int i = blockIdx.x * 256 + threadIdx.x;
    if (i >= NCOL * 800) return;
    int n = i / 800, k = i % 800;
    BhA[i] = (_Float16)((n < GATES) ? mlpw1[(size_t)n * 1600 + k]
                                    : mlpw1[(size_t)(n - GATES) * 1600 + 800 + k]);
}

// ---------------------------------------------------------------- MFMA f16 GEMM (verified R6)
__global__ __launch_bounds__(256) void gemm_f16(
    const _Float16* __restrict__ A, int Kp,
    const _Float16* __restrict__ B,
    const float* __restrict__ bias, float* __restrict__ C)
{
    const int tid  = threadIdx.x;
    const int w    = tid >> 6, lane = tid & 63;
    const int quad = lane >> 4, l16 = lane & 15;
    const int mb   = blockIdx.y * 32 + (w & 1) * 16;
    const int n0   = blockIdx.x * 64 + (w >> 1) * 32;
    const _Float16* Arow = A + (size_t)(mb + l16) * Kp + quad * 8;
    const _Float16* B0r  = B + (size_t)(n0 + l16) * Kp + quad * 8;
    const _Float16* B1r  = B0r + (size_t)16 * Kp;
    f32x4 acc0 = {0.f, 0.f, 0.f, 0.f}, acc1 = {0.f, 0.f, 0.f, 0.f};
#pragma unroll 4
    for (int k0 = 0; k0 < Kp; k0 += 32) {
        f16x8 a  = *(const f16x8*)(Arow + k0);
        f16x8 b0 = *(const f16x8*)(B0r + k0);
        f16x8 b1 = *(const f16x8*)(B1r + k0);
        acc0 = __builtin_amdgcn_mfma_f32_16x16x32_f16(a, b0, acc0, 0, 0, 0);
        acc1 = __builtin_amdgcn_mfma_f32_16x16x32_f16(a, b1, acc1, 0, 0, 0);
    }
    const int mr = mb + quad * 4;
    float bn0 = bias[n0 + l16], bn1 = bias[n0 + 16 + l16];
#pragma unroll
    for (int r = 0; r < 4; ++r) {
        C[(size_t)(mr + r) * NCOL + n0 + l16]      = acc0[r] + bn0;
        C[(size_t)(mr + r) * NCOL + n0 + 16 + l16] = acc1[r] + bn1;
    }
}

// ---------------------------------------------------------------- recurrence
// R8: direct register polling — no LDS h staging, ONE barrier per step.
// Thread (gate g, k-quarter kq, half) dots 2 producer lines p0=4kq+2*half+{0,1}
// (13 dwords = 26 fp16 each, line-aligned to the 25-row producer blocks).
// It atomically loads those 26 dwords from L3 each step, spins on the
// 0xFFFFFFFF sentinel in-register, fdot2s against 26 matching packed weight
// regs. part[] double-buffered by step parity. Boundary h0 lines prefilled
// at slots 0/321 by prep (no s==0 special case).
__global__ __launch_bounds__(1024, 4) void lstm_layer(
    const float* __restrict__ gates,   // SEQ x 3200 (x@W_ih^T + biases)
    const float* __restrict__ whh_f, const float* __restrict__ whh_b,
    const float* __restrict__ c0f, const float* __restrict__ c0b,
    unsigned* __restrict__ ex,         // this layer's exchange region
    _Float16* __restrict__ ah)         // SEQ x 800 fp16 h (input to next GEMM)
{
    __shared__ float part[2][16][28];
    const int tid = threadIdx.x;
    const int dir = blockIdx.x >> 4;
    const int wg  = blockIdx.x & 15;
    const int j0  = wg * RPW;
    const float* whh = dir ? whh_b : whh_f;
    const float* c0d = dir ? c0b : c0f;

    const int w    = tid >> 6;         // wave 0..15
    const int lane = tid & 63;
    const int g    = w & 3;            // gate
    const int kq   = w >> 2;           // k-quarter (4 producer lines)
    const int half = lane & 1;         // line-pair select within quarter
    const int r    = lane >> 1;        // row within WG (active if r<25)
    const bool act = (lane < 2 * RPW);
    const int jrow = j0 + (r < RPW ? r : RPW - 1);
    const int p0   = 4 * kq + 2 * half;
    const unsigned* exd = ex + (size_t)dir * (GDW * 322 * 16);
    const unsigned* LB0 = exd + (size_t)p0 * (322 * 16);
    const unsigned* LB1 = exd + (size_t)(p0 + 1) * (322 * 16);

    // one-time: 52 weights packed fp16 into 26 uints, aligned to line layout
    unsigned wr[26];
#pragma unroll
    for (int l = 0; l < 2; ++l) {
        const float* wsrc = whh + (size_t)(g * 400 + jrow) * 400 + (p0 + l) * RPW;
#pragma unroll
        for (int d = 0; d < 13; ++d) {
            float lo = wsrc[2 * d];
            float hi = (d < 12) ? wsrc[2 * d + 1] : 0.f;  // line pad slot
            H2U pk; pk.hh = __floats2half2_rn(lo, hi);
            wr[l * 13 + d] = pk.u;
        }
    }

    float c_prev = (tid < RPW) ? c0d[j0 + tid] : 0.f;

    for (int s = 0; s < 320; ++s) {
        const int row  = dir ? (319 - s) : s;
        const int slot = dir ? (row + 2) : row;   // consumer slot = rp+1

        // gate prefetch for activation threads (independent of h_prev)
        float gv0 = 0.f, gv1 = 0.f, gv2 = 0.f, gv3 = 0.f;
        if (tid < RPW) {
            const float* gx = gates + (size_t)row * NCOL + dir * GATES + j0 + tid;
            gv0 = gx[0]; gv1 = gx[400]; gv2 = gx[800]; gv3 = gx[1200];
        }

        float acc = 0.f;
        if (act) {
            const unsigned* L0 = LB0 + slot * 16;
            const unsigned* L1 = LB1 + slot * 16;
            unsigned ha[13], hb[13];
#pragma unroll
            for (int i = 0; i < 13; ++i)
                ha[i] = __hip_atomic_load(L0 + i, __ATOMIC_RELAXED, __HIP_MEMORY_SCOPE_AGENT);
#pragma unroll
            for (int i = 0; i < 13; ++i)
                hb[i] = __hip_atomic_load(L1 + i, __ATOMIC_RELAXED, __HIP_MEMORY_SCOPE_AGENT);
#pragma unroll
            for (int i = 0; i < 13; ++i)
                while (ha[i] == 0xFFFFFFFFu)
                    ha[i] = __hip_atomic_load(L0 + i, __ATOMIC_RELAXED, __HIP_MEMORY_SCOPE_AGENT);
#pragma unroll
            for (int i = 0; i < 13; ++i) {
                H2U wv, xv; wv.u = wr[i]; xv.u = ha[i];
                acc = __builtin_amdgcn_fdot2(wv.h, xv.h, acc, false);
            }
#pragma unroll
            for (int i = 0; i < 13; ++i)
                while (hb[i] == 0xFFFFFFFFu)
                    hb[i] = __hip_atomic_load(L1 + i, __ATOMIC_RELAXED, __HIP_MEMORY_SCOPE_AGENT);
#pragma unroll
            for (int i = 0; i < 13; ++i) {
                H2U wv, xv; wv.u = wr[13 + i]; xv.u = hb[i];
                acc = __builtin_amdgcn_fdot2(wv.h, xv.h, acc, false);
            }
        }
        acc += __shfl_xor(acc, 1, 64);       // combine the two line-pairs of row r
        if (act && half == 0) part[s & 1][w][r] = acc;
        __syncthreads();                     // the ONLY barrier per step

        float hv = 0.f;
        if (tid < RPW) {
            const float (*pb)[28] = part[s & 1];
            float gi = gv0 + ((pb[0][tid] + pb[4][tid]) + (pb[8][tid]  + pb[12][tid]));
            float gf = gv1 + ((pb[1][tid] + pb[5][tid]) + (pb[9][tid]  + pb[13][tid]));
            float gg = gv2 + ((pb[2][tid] + pb[6][tid]) + (pb[10][tid] + pb[14][tid]));
            float go = gv3 + ((pb[3][tid] + pb[7][tid]) + (pb[11][tid] + pb[15][tid]));
            float iv = 1.f / (1.f + __expf(-gi));
            float fv = 1.f / (1.f + __expf(-gf));
            float ov = 1.f / (1.f + __expf(-go));
            float tg = 1.f - 2.f / (1.f + __expf(2.f * gg));
            c_prev = fv * c_prev + iv * tg;
            float tc = 1.f - 2.f / (1.f + __expf(2.f * c_prev));
            hv = ov * tc;
        }
        if (w == 0) {
            int i0 = 2 * lane     < 63 ? 2 * lane     : 63;
            int i1 = 2 * lane + 1 < 63 ? 2 * lane + 1 : 63;
            float xlo = __shfl(hv, i0, 64);
            float xhi = __shfl(hv, i1, 64);
            if (lane < 13) {                 // one private 64B line per step
                H2U pk;
                pk.hh = __floats2half2_rn(xlo, (2 * lane + 1 < RPW) ? xhi : 0.f);
                unsigned* dst = (unsigned*)exd + ((size_t)wg * 322 + row + 1) * 16 + lane;
                __hip_atomic_store(dst, pk.u, __ATOMIC_RELAXED, __HIP_MEMORY_SCOPE_AGENT);
            }
            if (tid < RPW)                   // fp16 h for the next GEMM
                ah[(size_t)row * 800 + dir * 400 + j0 + tid] = (_Float16)hv;
        }
        // part[] hazards: writes go to buf (s&1), act reads same buf between
        // this barrier and the next poll-gated write of buf (s&1) at s+2,
        // which transitively requires our act(s+1) > act(s). safe.
    }
}

// ---------------------------------------------------------------- fused scorer (+ border rows)
__global__ __launch_bounds__(256) void scores_kernel(
    const float* __restrict__ ab, const float* __restrict__ w2,
    const float* __restrict__ b2, float* __restrict__ out)
{
    if (blockIdx.y == 20) {              // border: row 0 / col 0
        int i = blockIdx.x * 256 + threadIdx.y * 16 + threadIdx.x;
        if (blockIdx.x < 2 && i < 321) {
            out[i]               = (i == 0) ? 1.f : 0.f;
            out[(size_t)i * 321] = (i == 0) ? 1.f : 0.f;
        }
        return;
    }
    __shared__ float a_s[16 * 132];
    __shared__ float b_s[16 * 132];
    __shared__ float w_s[128];
    const int tx = threadIdx.x, ty = threadIdx.y;
    const int tid = ty * 16 + tx;
    const int n0 = blockIdx.y * 16, d0 = blockIdx.x * 16;
    float acc = 0.f;
    for (int kc = 0; kc < 1600; kc += 128) {
        for (int i = tid; i < 16 * 128; i += 256) {
            int r = i >> 7, c = i & 127;
            a_s[r * 132 + c] = ab[(size_t)(n0 + r) * NCOL + kc + c];
            b_s[r * 132 + c] = ab[(size_t)(d0 + r) * NCOL + 1600 + kc + c];
        }
        if (tid < 128) w_s[tid] = w2[kc + tid];
        __syncthreads();
#pragma unroll
        for (int k = 0; k < 128; k += 4) {
            float4 av = *(const float4*)&a_s[ty * 132 + k];
            float4 bv = *(const float4*)&b_s[tx * 132 + k];
            float4 wv = *(const float4*)&w_s[k];
            acc += fmaxf(av.x + bv.x, 0.f) * wv.x;
            acc += fmaxf(av.y + bv.y, 0.f) * wv.y;
            acc += fmaxf(av.z + bv.z, 0.f) * wv.z;
            acc += fmaxf(av.w + bv.w, 0.f) * wv.w;
        }
        __syncthreads();
    }
    int n = n0 + ty, d = d0 + tx;
    out[(size_t)(n + 1) * 321 + (d + 1)] = (n == d) ? 0.f : (acc + b2[0]);
}

// ---------------------------------------------------------------- launcher
extern "C" void kernel_launch(void* const* d_in, const int* in_sizes, int n_in,
                              void* d_out, int out_size, void* d_ws, size_t ws_size,
                              hipStream_t stream)
{
    const int*   words    = (const int*)d_in[0];
    const int*   tags     = (const int*)d_in[1];
    const float* wemb     = (const float*)d_in[3];
    const float* temb     = (const float*)d_in[4];
    const float* h0       = (const float*)d_in[5];
    const float* c0       = (const float*)d_in[6];
    const float* w_ih_l0  = (const float*)d_in[7];
    const float* w_hh_l0  = (const float*)d_in[8];
    const float* b_ih_l0  = (const float*)d_in[9];
    const float* b_hh_l0  = (const float*)d_in[10];
    const float* w_ih_l0r = (const float*)d_in[11];
    const float* w_hh_l0r = (const float*)d_in[12];
    const float* b_ih_l0r = (const float*)d_in[13];
    const float* b_hh_l0r = (const float*)d_in[14];
    const float* w_ih_l1  = (const float*)d_in[15];
    const float* w_hh_l1  = (const float*)d_in[16];
    const float* b_ih_l1  = (const float*)d_in[17];
    const float* b_hh_l1  = (const float*)d_in[18];
    const float* w_ih_l1r = (const float*)d_in[19];
    const float* w_hh_l1r = (const float*)d_in[20];
    const float* b_ih_l1r = (const float*)d_in[21];
    const float* b_hh_l1r = (const float*)d_in[22];
    const float* mlp_w1   = (const float*)d_in[23];
    const float* mlp_b1   = (const float*)d_in[24];
    const float* mlp_w2   = (const float*)d_in[25];
    const float* mlp_b2   = (const float*)d_in[26];
    float* out = (float*)d_out;

    float* ws = (float*)d_ws;
    float*    gates  = ws;                          // 320*3200 f32
    float*    biasL0 = ws + 1024000;
    float*    biasL1 = ws + 1027200;
    float*    biasAB = ws + 1030400;
    unsigned* ex     = (unsigned*)(ws + 1033600);   // 2 layers x EXL dwords
    _Float16* Ah0    = (_Float16*)(ws + 1363328);   // 320*416 halves
    _Float16* Ah1    = (_Float16*)(ws + 1429888);   // 320*800 halves
    _Float16* Ah2    = (_Float16*)(ws + 1557888);   // 320*800 halves
    _Float16* BhA    = (_Float16*)(ws + 1685888);   // 3200x800 halves (reused)
    _Float16* BhB    = (_Float16*)(ws + 2965888);   // 3200x800 halves
    unsigned* ex0 = ex, *ex1 = ex + EXL;

    // sentinel-fill the exchange (data doubles as ready flag)
    hipMemsetAsync(ex, 0xFF, (size_t)2 * EXL * 4, stream);

    prep_kernel<<<15734, 256, 0, stream>>>(
        words, tags, wemb, temb, Ah0,
        b_ih_l0, b_hh_l0, b_ih_l0r, b_hh_l0r,
        b_ih_l1, b_hh_l1, b_ih_l1r, b_hh_l1r,
        mlp_b1, biasL0, biasL1, biasAB,
        w_ih_l0, w_ih_l0r, BhA, w_ih_l1, w_ih_l1r, BhB, h0, ex);

    gemm_f16<<<dim3(50, 10), 256, 0, stream>>>(Ah0, 416, BhA, biasL0, gates);
    cvtMLP_kernel<<<10000, 256, 0, stream>>>(mlp_w1, BhA);
    lstm_layer<<<2 * GDW, 1024, 0, stream>>>(gates, w_hh_l0, w_hh_l0r,
                                             c0, c0 + 400, ex0, Ah1);
    gemm_f16<<<dim3(50, 10), 256, 0, stream>>>(Ah1, 800, BhB, biasL1, gates);
    lstm_layer<<<2 * GDW, 1024, 0, stream>>>(gates, w_hh_l1, w_hh_l1r,
                                             c0 + 800, c0 + 1200, ex1, Ah2);
    gemm_f16<<<dim3(50, 10), 256, 0, stream>>>(Ah2, 800, BhA, biasAB, gates);

    scores_kernel<<<dim3(20, 21), dim3(16, 16), 0, stream>>>(gates, mlp_w2, mlp_b2, out);
}

// Round 9
// 1765.919 us; speedup vs baseline: 2.4406x; 2.4406x over previous
//
#include <hip/hip_runtime.h>
#include <hip/hip_bf16.h>
#include <hip/hip_fp16.h>

#define SEQ   320
#define GATES 1600
#define NCOL  3200
#define GDW   16            // workgroups per direction in the recurrent kernel
#define RPW   25            // h-rows owned per workgroup (400/16)
#define EXF   (322 * 512)   // dwords per direction per layer (322 slots x 16 prod x 32)
#define EXL   (2 * EXF)     // dwords per layer

typedef _Float16 half2v __attribute__((ext_vector_type(2)));
typedef _Float16 f16x8  __attribute__((ext_vector_type(8)));
typedef float    f32x4  __attribute__((ext_vector_type(4)));
union H2U { unsigned u; half2v h; __half2 hh; };

// ---------------------------------------------------------------- prep: embed->f16, bias, cvt W_ih_l0/l1, ex slot-0 fill
__global__ __launch_bounds__(256) void prep_kernel(
    const int* __restrict__ words, const int* __restrict__ tags,
    const float* __restrict__ wemb, const float* __restrict__ temb,
    _Float16* __restrict__ Ah0,
    const float* __restrict__ bihl0,  const float* __restrict__ bhhl0,
    const float* __restrict__ bihl0r, const float* __restrict__ bhhl0r,
    const float* __restrict__ bihl1,  const float* __restrict__ bhhl1,
    const float* __restrict__ bihl1r, const float* __restrict__ bhhl1r,
    const float* __restrict__ mlpb1,
    float* __restrict__ bL0, float* __restrict__ bL1, float* __restrict__ bAB,
    const float* __restrict__ wih0, const float* __restrict__ wih0r,
    _Float16* __restrict__ BhA,
    const float* __restrict__ wih1, const float* __restrict__ wih1r,
    _Float16* __restrict__ BhB,
    const float* __restrict__ h0, unsigned* __restrict__ ex)
{
    const int b = blockIdx.x, t = threadIdx.x;
    if (b < 520) {                       // embeddings -> Ah0 (320 x 416, zero-pad)
        int i = b * 256 + t;
        if (i >= SEQ * 416) return;
        int tt = i / 416, c = i % 416;
        float v = 0.f;
        if (c < 300)      v = wemb[(size_t)words[tt] * 300 + c];
        else if (c < 400) v = temb[(size_t)tags[tt] * 100 + (c - 300)];
        Ah0[i] = (_Float16)v;
    } else if (b < 533) {                // bias sums
        int g = (b - 520) * 256 + t;
        if (g >= NCOL) return;
        if (g < GATES) {
            bL0[g] = bihl0[g] + bhhl0[g];
            bL1[g] = bihl1[g] + bhhl1[g];
            bAB[g] = mlpb1[g];
        } else {
            int q = g - GATES;
            bL0[g] = bihl0r[q] + bhhl0r[q];
            bL1[g] = bihl1r[q] + bhhl1r[q];
            bAB[g] = 0.f;
        }
    } else if (b < 5733) {               // W_ih_l0 -> fp16 (3200 x 416)
        int i = (b - 533) * 256 + t;
        if (i >= NCOL * 416) return;
        int n = i / 416, k = i % 416;
        float v = 0.f;
        if (k < 400)
            v = (n < GATES) ? wih0[(size_t)n * 400 + k]
                            : wih0r[(size_t)(n - GATES) * 400 + k];
        BhA[i] = (_Float16)v;
    } else if (b < 15733) {              // W_ih_l1 -> fp16 (3200 x 800)
        int i = (b - 5733) * 256 + t;
        if (i >= NCOL * 800) return;
        int n = i / 800, k = i % 800;
        BhB[i] = (_Float16)((n < GATES) ? wih1[(size_t)n * 800 + k]
                                        : wih1r[(size_t)(n - GATES) * 800 + k]);
    } else {                             // h0 -> exchange slot 0 (fp32), all layers/dirs
        int i = (b - 15733) * 256 + t;
        if (i >= 1600) return;
        int layer = i / 800, rem = i % 800, dir = rem / 400, j = rem % 400;
        int p = j / 25, r = j % 25;
        ex[(size_t)layer * EXL + (size_t)dir * EXF + p * 32 + r] =
            __float_as_uint(h0[(size_t)(layer * 2 + dir) * 400 + j]);
    }
}

// ---------------------------------------------------------------- cvt mlp_w1 -> BhA (after gemm0 frees it)
__global__ __launch_bounds__(256) void cvtMLP_kernel(
    const float* __restrict__ mlpw1, _Float16* __restrict__ BhA)
{
    int i = blockIdx.x * 256 + threadIdx.x;
    if (i >= NCOL * 800) return;
    int n = i / 800, k = i % 800;
    BhA[i] = (_Float16)((n < GATES) ? mlpw1[(size_t)n * 1600 + k]
                                    : mlpw1[(size_t)(n - GATES) * 1600 + 800 + k]);
}

// ---------------------------------------------------------------- MFMA f16 GEMM (verified R6)
__global__ __launch_bounds__(256) void gemm_f16(
    const _Float16* __restrict__ A, int Kp,
    const _Float16* __restrict__ B,
    const float* __restrict__ bias, float* __restrict__ C)
{
    const int tid  = threadIdx.x;
    const int w    = tid >> 6, lane = tid & 63;
    const int quad = lane >> 4, l16 = lane & 15;
    const int mb   = blockIdx.y * 32 + (w & 1) * 16;
    const int n0   = blockIdx.x * 64 + (w >> 1) * 32;
    const _Float16* Arow = A + (size_t)(mb + l16) * Kp + quad * 8;
    const _Float16* B0r  = B + (size_t)(n0 + l16) * Kp + quad * 8;
    const _Float16* B1r  = B0r + (size_t)16 * Kp;
    f32x4 acc0 = {0.f, 0.f, 0.f, 0.f}, acc1 = {0.f, 0.f, 0.f, 0.f};
#pragma unroll 4
    for (int k0 = 0; k0 < Kp; k0 += 32) {
        f16x8 a  = *(const f16x8*)(Arow + k0);
        f16x8 b0 = *(const f16x8*)(B0r + k0);
        f16x8 b1 = *(const f16x8*)(B1r + k0);
        acc0 = __builtin_amdgcn_mfma_f32_16x16x32_f16(a, b0, acc0, 0, 0, 0);
        acc1 = __builtin_amdgcn_mfma_f32_16x16x32_f16(a, b1, acc1, 0, 0, 0);
    }
    const int mr = mb + quad * 4;
    float bn0 = bias[n0 + l16], bn1 = bias[n0 + 16 + l16];
#pragma unroll
    for (int r = 0; r < 4; ++r) {
        C[(size_t)(mr + r) * NCOL + n0 + l16]      = acc0[r] + bn0;
        C[(size_t)(mr + r) * NCOL + n0 + 16 + l16] = acc1[r] + bn1;
    }
}

// ---------------------------------------------------------------- recurrence
// R9: one barrier/step; wave-local reduction.
// Wave w (<13) owns rows 2w, 2w+1. lane = ri*32 + g*8 + ks: ri=row, g=gate,
// ks=k-slice (chunks k=4*(ks+8i), i<13). k-reduce = 3 shfl_xor; gate gather
// = 3 shfl; act on 25 lanes across 13 waves; per-row fp32 store to exchange.
// Exchange: [dir][slot 0..321][producer*32 + r] fp32; slot s = h after step
// s-1 (slot 0 = h0, prep-filled). Producer lines private (32-float blocks);
// consumer pollers (375 threads, contiguous dwords) are coalesced — the
// R8 lesson: never per-lane same-address atomic fan-out.
__global__ __launch_bounds__(1024, 4) void lstm_layer(
    const float* __restrict__ gates,   // SEQ x 3200 (x@W_ih^T + biases)
    const float* __restrict__ whh_f, const float* __restrict__ whh_b,
    const float* __restrict__ c0f, const float* __restrict__ c0b,
    unsigned* __restrict__ ex,         // this layer's exchange region
    _Float16* __restrict__ ah)         // SEQ x 800 fp16 h (input to next GEMM)
{
    __shared__ unsigned h_pk[2][208];  // 416 halves per buffer (pad 400..415 = 0)
    const int tid = threadIdx.x;
    const int dir = blockIdx.x >> 4;
    const int wg  = blockIdx.x & 15;
    const int j0  = wg * RPW;
    const float* whh = dir ? whh_b : whh_f;
    const float* c0d = dir ? c0b : c0f;
    unsigned* exd = ex + (size_t)dir * EXF;

    const int w    = tid >> 6;         // wave 0..15 (13..15 barrier-only)
    const int lane = tid & 63;
    const int ri   = lane >> 5;        // row within wave
    const int g    = (lane >> 3) & 3;  // gate
    const int ks   = lane & 7;         // k-slice
    const int rloc = 2 * w + ri;
    const bool dotw = (w < 13) && (rloc < RPW);
    const int j    = j0 + (dotw ? rloc : 0);
    const bool actl = dotw && (g == 0) && (ks == 0);

    // one-time: 52 weights (13 chunks of 4), fp16-packed into 26 uints
    unsigned wr[26];
#pragma unroll
    for (int i = 0; i < 26; ++i) wr[i] = 0u;
    if (dotw) {
        const float* wb = whh + (size_t)(g * 400 + j) * 400;
#pragma unroll
        for (int i = 0; i < 13; ++i) {
            int k0 = 4 * (ks + 8 * i);
            float f0 = (k0 + 0 < 400) ? wb[k0 + 0] : 0.f;
            float f1 = (k0 + 1 < 400) ? wb[k0 + 1] : 0.f;
            float f2 = (k0 + 2 < 400) ? wb[k0 + 2] : 0.f;
            float f3 = (k0 + 3 < 400) ? wb[k0 + 3] : 0.f;
            H2U a, c;
            a.hh = __floats2half2_rn(f0, f1);
            c.hh = __floats2half2_rn(f2, f3);
            wr[2 * i] = a.u; wr[2 * i + 1] = c.u;
        }
    }

    // init: own rows of h0 into buffer 0; zero the pad halves of both buffers
    if (tid >= 512 && tid < 512 + RPW) {
        int r = tid - 512;
        float v = __uint_as_float(exd[wg * 32 + r]);   // slot 0, own block
        H2U t2; t2.hh = __floats2half2_rn(v, 0.f);
        ((unsigned short*)h_pk[0])[j0 + r] = (unsigned short)t2.u;
    }
    if (tid >= 544 && tid < 560) {
        ((unsigned short*)h_pk[0])[400 + tid - 544] = 0;
        ((unsigned short*)h_pk[1])[400 + tid - 544] = 0;
    }

    float c_prev = actl ? c0d[j] : 0.f;

    const int pidx = tid / 25;                 // poller: producer index (15 remote)
    const int prow = tid - pidx * 25;
    const int pp   = pidx + (pidx >= wg ? 1 : 0);
    const bool poller = (tid < 375);

    for (int s = 0; s < 320; ++s) {
        const int row = dir ? (319 - s) : s;

        // gate prefetch (independent of h_prev, overlaps the poll)
        float gv0 = 0.f, gv1 = 0.f, gv2 = 0.f, gv3 = 0.f;
        if (actl) {
            const float* gx = gates + (size_t)row * NCOL + dir * GATES + j;
            gv0 = gx[0]; gv1 = gx[400]; gv2 = gx[800]; gv3 = gx[1200];
        }

        if (poller) {
            const unsigned* src = exd + (size_t)s * 512 + pp * 32 + prow;
            unsigned v = __hip_atomic_load(src, __ATOMIC_RELAXED, __HIP_MEMORY_SCOPE_AGENT);
            while (v == 0xFFFFFFFFu)
                v = __hip_atomic_load(src, __ATOMIC_RELAXED, __HIP_MEMORY_SCOPE_AGENT);
            H2U t2; t2.hh = __floats2half2_rn(__uint_as_float(v), 0.f);
            ((unsigned short*)h_pk[s & 1])[pp * 25 + prow] = (unsigned short)t2.u;
        }
        __syncthreads();                       // the ONLY barrier per step

        float acc = 0.f;
        if (dotw) {
            const uint2* hb = (const uint2*)h_pk[s & 1];
#pragma unroll
            for (int i = 0; i < 13; ++i) {
                uint2 hv = hb[ks + 8 * i];
                H2U w0, w1, x0, x1;
                w0.u = wr[2 * i]; w1.u = wr[2 * i + 1];
                x0.u = hv.x;      x1.u = hv.y;
                acc = __builtin_amdgcn_fdot2(w0.h, x0.h, acc, false);
                acc = __builtin_amdgcn_fdot2(w1.h, x1.h, acc, false);
            }
        }
        acc += __shfl_xor(acc, 1, 64);         // reduce over ks (wave-local)
        acc += __shfl_xor(acc, 2, 64);
        acc += __shfl_xor(acc, 4, 64);
        float p1 = __shfl(acc, (lane & 32) + 8,  64);   // gate gather
        float p2 = __shfl(acc, (lane & 32) + 16, 64);
        float p3 = __shfl(acc, (lane & 32) + 24, 64);

        if (actl) {
            float gi = gv0 + acc;
            float gf = gv1 + p1;
            float gg = gv2 + p2;
            float go = gv3 + p3;
            float iv = 1.f / (1.f + __expf(-gi));
            float fv = 1.f / (1.f + __expf(-gf));
            float ov = 1.f / (1.f + __expf(-go));
            float tg = 1.f - 2.f / (1.f + __expf(2.f * gg));
            c_prev = fv * c_prev + iv * tg;
            float tc = 1.f - 2.f / (1.f + __expf(2.f * c_prev));
            float hv = ov * tc;
            // store first: start the L3 trip ASAP
            __hip_atomic_store(exd + (size_t)(s + 1) * 512 + wg * 32 + rloc,
                               __float_as_uint(hv), __ATOMIC_RELAXED,
                               __HIP_MEMORY_SCOPE_AGENT);
            H2U t2; t2.hh = __floats2half2_rn(hv, 0.f);
            ((unsigned short*)h_pk[(s + 1) & 1])[j] = (unsigned short)t2.u;
            ah[(size_t)row * 800 + dir * 400 + j] = (_Float16)hv;
        }
        // LDS hazards: pollers/act write buf[(s)&1]/[(s+1)&1] resp.; readers of
        // a buffer at iter s finished before barrier(s+1) which precedes any
        // re-write of that buffer (iter s+2 pre-barrier / s+1 post-barrier,
        // disjoint own/remote halves). Single barrier is sufficient.
    }
}

// ---------------------------------------------------------------- fused scorer (+ border rows)
__global__ __launch_bounds__(256) void scores_kernel(
    const float* __restrict__ ab, const float* __restrict__ w2,
    const float* __restrict__ b2, float* __restrict__ out)
{
    if (blockIdx.y == 20) {              // border: row 0 / col 0
        int i = blockIdx.x * 256 + threadIdx.y * 16 + threadIdx.x;
        if (blockIdx.x < 2 && i < 321) {
            out[i]               = (i == 0) ? 1.f : 0.f;
            out[(size_t)i * 321] = (i == 0) ? 1.f : 0.f;
        }
        return;
    }
    __shared__ float a_s[16 * 132];
    __shared__ float b_s[16 * 132];
    __shared__ float w_s[128];
    const int tx = threadIdx.x, ty = threadIdx.y;
    const int tid = ty * 16 + tx;
    const int n0 = blockIdx.y * 16, d0 = blockIdx.x * 16;
    float acc = 0.f;
    for (int kc = 0; kc < 1600; kc += 128) {
        for (int i = tid; i < 16 * 128; i += 256) {
            int r = i >> 7, c = i & 127;
            a_s[r * 132 + c] = ab[(size_t)(n0 + r) * NCOL + kc + c];
            b_s[r * 132 + c] = ab[(size_t)(d0 + r) * NCOL + 1600 + kc + c];
        }
        if (tid < 128) w_s[tid] = w2[kc + tid];
        __syncthreads();
#pragma unroll
        for (int k = 0; k < 128; k += 4) {
            float4 av = *(const float4*)&a_s[ty * 132 + k];
            float4 bv = *(const float4*)&b_s[tx * 132 + k];
            float4 wv = *(const float4*)&w_s[k];
            acc += fmaxf(av.x + bv.x, 0.f) * wv.x;
            acc += fmaxf(av.y + bv.y, 0.f) * wv.y;
            acc += fmaxf(av.z + bv.z, 0.f) * wv.z;
            acc += fmaxf(av.w + bv.w, 0.f) * wv.w;
        }
        __syncthreads();
    }
    int n = n0 + ty, d = d0 + tx;
    out[(size_t)(n + 1) * 321 + (d + 1)] = (n == d) ? 0.f : (acc + b2[0]);
}

// ---------------------------------------------------------------- launcher
extern "C" void kernel_launch(void* const* d_in, const int* in_sizes, int n_in,
                              void* d_out, int out_size, void* d_ws, size_t ws_size,
                              hipStream_t stream)
{
    const int*   words    = (const int*)d_in[0];
    const int*   tags     = (const int*)d_in[1];
    const float* wemb     = (const float*)d_in[3];
    const float* temb     = (const float*)d_in[4];
    const float* h0       = (const float*)d_in[5];
    const float* c0       = (const float*)d_in[6];
    const float* w_ih_l0  = (const float*)d_in[7];
    const float* w_hh_l0  = (const float*)d_in[8];
    const float* b_ih_l0  = (const float*)d_in[9];
    const float* b_hh_l0  = (const float*)d_in[10];
    const float* w_ih_l0r = (const float*)d_in[11];
    const float* w_hh_l0r = (const float*)d_in[12];
    const float* b_ih_l0r = (const float*)d_in[13];
    const float* b_hh_l0r = (const float*)d_in[14];
    const float* w_ih_l1  = (const float*)d_in[15];
    const float* w_hh_l1  = (const float*)d_in[16];
    const float* b_ih_l1  = (const float*)d_in[17];
    const float* b_hh_l1  = (const float*)d_in[18];
    const float* w_ih_l1r = (const float*)d_in[19];
    const float* w_hh_l1r = (const float*)d_in[20];
    const float* b_ih_l1r = (const float*)d_in[21];
    const float* b_hh_l1r = (const float*)d_in[22];
    const float* mlp_w1   = (const float*)d_in[23];
    const float* mlp_b1   = (const float*)d_in[24];
    const float* mlp_w2   = (const float*)d_in[25];
    const float* mlp_b2   = (const float*)d_in[26];
    float* out = (float*)d_out;

    float* ws = (float*)d_ws;
    float*    gates  = ws;                          // 320*3200 f32
    float*    biasL0 = ws + 1024000;
    float*    biasL1 = ws + 1027200;
    float*    biasAB = ws + 1030400;
    unsigned* ex     = (unsigned*)(ws + 1033600);   // 2 layers x EXL dwords
    _Float16* Ah0    = (_Float16*)(ws + 1693056);   // 320*416 halves
    _Float16* Ah1    = (_Float16*)(ws + 1759616);   // 320*800 halves
    _Float16* Ah2    = (_Float16*)(ws + 1887616);   // 320*800 halves
    _Float16* BhA    = (_Float16*)(ws + 2015616);   // 3200x800 halves (reused)
    _Float16* BhB    = (_Float16*)(ws + 3295616);   // 3200x800 halves
    unsigned* ex0 = ex, *ex1 = ex + EXL;

    // sentinel-fill the exchange (data doubles as ready flag)
    hipMemsetAsync(ex, 0xFF, (size_t)2 * EXL * 4, stream);

    prep_kernel<<<15740, 256, 0, stream>>>(
        words, tags, wemb, temb, Ah0,
        b_ih_l0, b_hh_l0, b_ih_l0r, b_hh_l0r,
        b_ih_l1, b_hh_l1, b_ih_l1r, b_hh_l1r,
        mlp_b1, biasL0, biasL1, biasAB,
        w_ih_l0, w_ih_l0r, BhA, w_ih_l1, w_ih_l1r, BhB, h0, ex);

    gemm_f16<<<dim3(50, 10), 256, 0, stream>>>(Ah0, 416, BhA, biasL0, gates);
    cvtMLP_kernel<<<10000, 256, 0, stream>>>(mlp_w1, BhA);
    lstm_layer<<<2 * GDW, 1024, 0, stream>>>(gates, w_hh_l0, w_hh_l0r,
                                             c0, c0 + 400, ex0, Ah1);
    gemm_f16<<<dim3(50, 10), 256, 0, stream>>>(Ah1, 800, BhB, biasL1, gates);
    lstm_layer<<<2 * GDW, 1024, 0, stream>>>(gates, w_hh_l1, w_hh_l1r,
                                             c0 + 800, c0 + 1200, ex1, Ah2);
    gemm_f16<<<dim3(50, 10), 256, 0, stream>>>(Ah2, 800, BhA, biasAB, gates);

    scores_kernel<<<dim3(20, 21), dim3(16, 16), 0, stream>>>(gates, mlp_w2, mlp_b2, out);
}